// Round 6
// baseline (184.077 us; speedup 1.0000x reference)
//
#include <hip/hip_runtime.h>

// DecorrelationNormalization (group whitening), x: [32,64,64,256] f32 NHWC.
// N = 131072 rows of 256 channels (1 KB each), 16 groups of m=16.
// R6: R5 numerics; fix = memory-level parallelism. R5's k1 was LATENCY-bound
// (1 outstanding load/wave, VALUBusy 16%, HBM 0.7 TB/s, no spill traffic).
// Now each wave owns a contiguous 32-row strip, processes 4 rows/iter with a
// 4-row-ahead prefetch (4 independent 1 KB loads in flight per wave).

#define NROWS   131072
#define DENOMF  131071.0f
#define EPSV    0.001f

// ws float offsets
#define OFF_INV    0        // [16][256] inv_sqrt row-major
#define OFF_BIAS   4096     // [16][16]  bias_i = sum_k inv[i][k]*mu[k]
#define OFF_TRIM   4352     // [2432] combined tri+sx (atomic fallback mode)
#define OFF_RED    8192     // [8][2432] slice-reduced partials
#define OFF_PART   27648    // [nblk][2432] per-block partials
#define COMB       2432     // 16*136 tri + 256 sx
#define NSLICE     8

__device__ __forceinline__ float4 shfl_xor4(float4 v, int m) {
    float4 r;
    r.x = __shfl_xor(v.x, m, 64);
    r.y = __shfl_xor(v.y, m, 64);
    r.z = __shfl_xor(v.z, m, 64);
    r.w = __shfl_xor(v.w, m, 64);
    return r;
}

#define FMA4(A, V, S) \
    A.x = fmaf(V.x, S, A.x); A.y = fmaf(V.y, S, A.y); \
    A.z = fmaf(V.z, S, A.z); A.w = fmaf(V.w, S, A.w)

#define DOT4(O, A, V) \
    O = fmaf(A.x, V.x, O); O = fmaf(A.y, V.y, O); \
    O = fmaf(A.z, V.z, O); O = fmaf(A.w, V.w, O)

__device__ __forceinline__ void tri_add(float* sacc, int g, int j, int i2, float v) {
    if (i2 <= j)
        atomicAdd(&sacc[g * 136 + i2 * 16 - (i2 * (i2 - 1)) / 2 + (j - i2)], v);
}

__device__ __forceinline__ void fold4(float* sacc, int g, int q, int jj, int mm, float4 A) {
    const int j  = 4 * q + jj;
    const int cb = 4 * (q ^ mm);
    tri_add(sacc, g, j, cb + 0, A.x);
    tri_add(sacc, g, j, cb + 1, A.y);
    tri_add(sacc, g, j, cb + 2, A.z);
    tri_add(sacc, g, j, cb + 3, A.w);
}

// ---------------- Phase 1: stats ----------------
// grid nblk x 512 thr (8 waves). Wave wv owns rows [base + wv*rpw, +rpw),
// 4 rows per iter, prefetch 4 ahead. Lane l owns channels [4l,4l+4).
__global__ __launch_bounds__(512, 4) void k1_stats(const float* __restrict__ x,
                                                   float* __restrict__ ws, int nblk) {
    __shared__ float sacc[COMB];        // [0:2176) tri, [2176:2432) sx
    const int tid = threadIdx.x;
    for (int t = tid; t < COMB; t += 512) sacc[t] = 0.0f;
    __syncthreads();

    const int lane = tid & 63, wv = tid >> 6;
    const int q = lane & 3, g = lane >> 2;
    const int rpb   = NROWS / gridDim.x;   // rows per block
    const int rpw   = rpb / 8;             // rows per wave (contiguous)
    const int iters = rpw / 4;
    const size_t rowbase = (size_t)blockIdx.x * rpb + (size_t)wv * rpw;
    const float4* wp = reinterpret_cast<const float4*>(x) + rowbase * 64 + lane;

    float4 a00 = {0,0,0,0}, a01 = {0,0,0,0}, a02 = {0,0,0,0}, a03 = {0,0,0,0};
    float4 a10 = {0,0,0,0}, a11 = {0,0,0,0}, a12 = {0,0,0,0}, a13 = {0,0,0,0};
    float4 a20 = {0,0,0,0}, a21 = {0,0,0,0}, a22 = {0,0,0,0}, a23 = {0,0,0,0};
    float4 a30 = {0,0,0,0}, a31 = {0,0,0,0}, a32 = {0,0,0,0}, a33 = {0,0,0,0};
    float4 s4v = {0,0,0,0};

#define PROC1(V)                                                              \
    {                                                                         \
        float4 v0 = (V);                                                      \
        float4 v1 = shfl_xor4(v0, 1);                                         \
        float4 v2 = shfl_xor4(v0, 2);                                         \
        float4 v3 = shfl_xor4(v0, 3);                                         \
        s4v.x += v0.x; s4v.y += v0.y; s4v.z += v0.z; s4v.w += v0.w;           \
        FMA4(a00, v0, v0.x); FMA4(a01, v1, v0.x); FMA4(a02, v2, v0.x); FMA4(a03, v3, v0.x); \
        FMA4(a10, v0, v0.y); FMA4(a11, v1, v0.y); FMA4(a12, v2, v0.y); FMA4(a13, v3, v0.y); \
        FMA4(a20, v0, v0.z); FMA4(a21, v1, v0.z); FMA4(a22, v2, v0.z); FMA4(a23, v3, v0.z); \
        FMA4(a30, v0, v0.w); FMA4(a31, v1, v0.w); FMA4(a32, v2, v0.w); FMA4(a33, v3, v0.w); \
    }

    float4 c0 = wp[0], c1 = wp[64], c2 = wp[128], c3 = wp[192];
    for (int i = 0; i < iters; ++i) {
        float4 n0, n1, n2, n3;
        const bool more = (i + 1 < iters);
        if (more) {
            const float4* np = wp + (size_t)(i + 1) * 256;
            n0 = np[0]; n1 = np[64]; n2 = np[128]; n3 = np[192];
        }
        PROC1(c0); PROC1(c1); PROC1(c2); PROC1(c3);
        if (more) { c0 = n0; c1 = n1; c2 = n2; c3 = n3; }
    }
#undef PROC1

    // fold the 4x16 rectangle into the per-group triangle (i2 <= j only)
    fold4(sacc, g, q, 0, 0, a00); fold4(sacc, g, q, 0, 1, a01);
    fold4(sacc, g, q, 0, 2, a02); fold4(sacc, g, q, 0, 3, a03);
    fold4(sacc, g, q, 1, 0, a10); fold4(sacc, g, q, 1, 1, a11);
    fold4(sacc, g, q, 1, 2, a12); fold4(sacc, g, q, 1, 3, a13);
    fold4(sacc, g, q, 2, 0, a20); fold4(sacc, g, q, 2, 1, a21);
    fold4(sacc, g, q, 2, 2, a22); fold4(sacc, g, q, 2, 3, a23);
    fold4(sacc, g, q, 3, 0, a30); fold4(sacc, g, q, 3, 1, a31);
    fold4(sacc, g, q, 3, 2, a32); fold4(sacc, g, q, 3, 3, a33);

    atomicAdd(&sacc[2176 + 4 * lane + 0], s4v.x);
    atomicAdd(&sacc[2176 + 4 * lane + 1], s4v.y);
    atomicAdd(&sacc[2176 + 4 * lane + 2], s4v.z);
    atomicAdd(&sacc[2176 + 4 * lane + 3], s4v.w);
    __syncthreads();

    if (nblk > 0) {
        float* dst = ws + OFF_PART + (size_t)blockIdx.x * COMB;
        for (int t = tid; t < COMB; t += 512) dst[t] = sacc[t];
    } else {
        for (int t = tid; t < COMB; t += 512) atomicAdd(&ws[OFF_TRIM + t], sacc[t]);
    }
}

// ---------------- Phase 2a: parallel partial reduction ----------------
__global__ __launch_bounds__(256, 4) void k2_reduce(float* __restrict__ ws, int nblk) {
    const int t = blockIdx.x * 256 + threadIdx.x;
    if (t >= COMB) return;
    const int per = nblk / NSLICE;
    const float* p = ws + OFF_PART + (size_t)(blockIdx.y * per) * COMB + t;
    float sum = 0.0f;
#pragma unroll 8
    for (int b = 0; b < per; ++b) sum += p[(size_t)b * COMB];
    ws[OFF_RED + (size_t)blockIdx.y * COMB + t] = sum;
}

// ---------------- Phase 2b: cov -> cholesky -> inverse -> bias ----------------
__global__ void k2_chol(float* __restrict__ ws, int nblk) {
    __shared__ float ct[136];
    __shared__ float cs[16];
    const int g = blockIdx.x, tid = threadIdx.x;

    if (nblk > 0) {
        for (int e = tid; e < 152; e += 64) {
            const int src = (e < 136) ? (g * 136 + e) : (2176 + g * 16 + (e - 136));
            float sum = 0.0f;
#pragma unroll
            for (int y = 0; y < NSLICE; ++y) sum += ws[OFF_RED + (size_t)y * COMB + src];
            if (e < 136) ct[e] = sum; else cs[e - 136] = sum;
        }
    } else {
        for (int e = tid; e < 152; e += 64) {
            const int src = (e < 136) ? (g * 136 + e) : (2176 + g * 16 + (e - 136));
            float v = ws[OFF_TRIM + src];
            if (e < 136) ct[e] = v; else cs[e - 136] = v;
        }
    }
    __syncthreads();

    const int ii = tid & 15;
    const float inv_denom = 1.0f / DENOMF;
    const float mu_l = cs[ii] * (1.0f / (float)NROWS);

    float arow[16];
#pragma unroll
    for (int k = 0; k < 16; ++k) {
        const int lo = (ii < k) ? ii : k;
        const int hi = (ii < k) ? k : ii;
        float sxx = ct[lo * 16 - (lo * (lo - 1)) / 2 + (hi - lo)];
        float mu_k = __shfl(mu_l, k, 64);
        float cv = (sxx - (float)NROWS * mu_l * mu_k) * inv_denom;   // /(N-1)
        cv = cv * (1.0f - EPSV) + ((k == ii) ? EPSV : 0.0f);         // shrink
        arow[k] = cv * inv_denom;                                    // faithful 2nd /(N-1)
    }

    float lrow[16];
#pragma unroll
    for (int j = 0; j < 16; ++j) {
        float diag = __shfl(arow[j], j, 64);
        float ljj  = sqrtf(diag);
        float lij  = (ii == j) ? ljj : arow[j] / ljj;
        lrow[j] = lij;
#pragma unroll
        for (int k = j + 1; k < 16; ++k) {
            float lkj = __shfl(lij, k, 64);
            arow[k] = fmaf(-lij, lkj, arow[k]);
        }
    }

    float xcol[16];
#pragma unroll
    for (int i2 = 0; i2 < 16; ++i2) {
        float ssum = (ii == i2) ? 1.0f : 0.0f;
#pragma unroll
        for (int k = 0; k < 16; ++k) {
            if (k < i2) {
                float Lik = __shfl(lrow[k], i2, 64);
                ssum = fmaf(-Lik, xcol[k], ssum);
            }
        }
        float Lii = __shfl(lrow[i2], i2, 64);
        xcol[i2] = (i2 >= ii) ? ssum / Lii : 0.0f;
    }

    float* invg = ws + OFF_INV + g * 256;
#pragma unroll
    for (int i2 = 0; i2 < 16; ++i2) {
        if (tid < 16) invg[i2 * 16 + tid] = xcol[i2];
        float bi = xcol[i2] * mu_l;
        bi += __shfl_xor(bi, 1, 64);
        bi += __shfl_xor(bi, 2, 64);
        bi += __shfl_xor(bi, 4, 64);
        bi += __shfl_xor(bi, 8, 64);
        if (tid == 0) ws[OFF_BIAS + g * 16 + i2] = bi;
    }
}

// ---------------- Phase 3: apply out = inv*x - bias ----------------
// grid 1024 x 256 thr (4 waves). Wave owns contiguous 32-row strip,
// 4 rows/iter with 4-ahead prefetch. ir<r><m> = inv row 4q+r, cols 4(q^m).
__global__ __launch_bounds__(256, 4) void k3_apply(const float* __restrict__ x,
                                                   const float* __restrict__ ws,
                                                   float* __restrict__ out) {
    const int tid = threadIdx.x, lane = tid & 63, wv = tid >> 6;
    const int q = lane & 3, g = lane >> 2;

    const float* invg = ws + OFF_INV + g * 256;
#define LOADIR(R, M) \
    *reinterpret_cast<const float4*>(invg + (4 * q + (R)) * 16 + 4 * (q ^ (M)))
    float4 ir00 = LOADIR(0, 0), ir01 = LOADIR(0, 1), ir02 = LOADIR(0, 2), ir03 = LOADIR(0, 3);
    float4 ir10 = LOADIR(1, 0), ir11 = LOADIR(1, 1), ir12 = LOADIR(1, 2), ir13 = LOADIR(1, 3);
    float4 ir20 = LOADIR(2, 0), ir21 = LOADIR(2, 1), ir22 = LOADIR(2, 2), ir23 = LOADIR(2, 3);
    float4 ir30 = LOADIR(3, 0), ir31 = LOADIR(3, 1), ir32 = LOADIR(3, 2), ir33 = LOADIR(3, 3);
#undef LOADIR
    float4 b4 = *reinterpret_cast<const float4*>(ws + OFF_BIAS + g * 16 + 4 * q);

    const int rpb   = NROWS / gridDim.x;   // 128
    const int rpw   = rpb / 4;              // 32 rows per wave
    const int iters = rpw / 4;              // 8
    const size_t rowbase = (size_t)blockIdx.x * rpb + (size_t)wv * rpw;
    const float4* wp = reinterpret_cast<const float4*>(x) + rowbase * 64 + lane;
    float4*       op = reinterpret_cast<float4*>(out)     + rowbase * 64 + lane;

#define PROC3(V, IDX)                                                         \
    {                                                                         \
        float4 v0 = (V);                                                      \
        float4 v1 = shfl_xor4(v0, 1);                                         \
        float4 v2 = shfl_xor4(v0, 2);                                         \
        float4 v3 = shfl_xor4(v0, 3);                                         \
        float o0 = -b4.x, o1 = -b4.y, o2 = -b4.z, o3 = -b4.w;                 \
        DOT4(o0, ir00, v0); DOT4(o0, ir01, v1); DOT4(o0, ir02, v2); DOT4(o0, ir03, v3); \
        DOT4(o1, ir10, v0); DOT4(o1, ir11, v1); DOT4(o1, ir12, v2); DOT4(o1, ir13, v3); \
        DOT4(o2, ir20, v0); DOT4(o2, ir21, v1); DOT4(o2, ir22, v2); DOT4(o2, ir23, v3); \
        DOT4(o3, ir30, v0); DOT4(o3, ir31, v1); DOT4(o3, ir32, v2); DOT4(o3, ir33, v3); \
        op[(size_t)(IDX) * 64] = make_float4(o0, o1, o2, o3);                 \
    }

    float4 c0 = wp[0], c1 = wp[64], c2 = wp[128], c3 = wp[192];
    for (int i = 0; i < iters; ++i) {
        float4 n0, n1, n2, n3;
        const bool more = (i + 1 < iters);
        if (more) {
            const float4* np = wp + (size_t)(i + 1) * 256;
            n0 = np[0]; n1 = np[64]; n2 = np[128]; n3 = np[192];
        }
        PROC3(c0, i * 4 + 0); PROC3(c1, i * 4 + 1);
        PROC3(c2, i * 4 + 2); PROC3(c3, i * 4 + 3);
        if (more) { c0 = n0; c1 = n1; c2 = n2; c3 = n3; }
    }
#undef PROC3
}

extern "C" void kernel_launch(void* const* d_in, const int* in_sizes, int n_in,
                              void* d_out, int out_size, void* d_ws, size_t ws_size,
                              hipStream_t stream) {
    const float* x = (const float*)d_in[0];
    float* out = (float*)d_out;
    float* ws  = (float*)d_ws;

    int nblk = 0;
    if (ws_size >= (size_t)(OFF_PART + 512 * COMB) * sizeof(float)) nblk = 512;
    else if (ws_size >= (size_t)(OFF_PART + 256 * COMB) * sizeof(float)) nblk = 256;

    if (nblk == 0) {
        hipMemsetAsync(ws + OFF_TRIM, 0, COMB * sizeof(float), stream);
        k1_stats<<<512, 512, 0, stream>>>(x, ws, 0);
        k2_chol <<<16, 64, 0, stream>>>(ws, 0);
    } else {
        k1_stats<<<nblk, 512, 0, stream>>>(x, ws, nblk);
        dim3 rg((COMB + 255) / 256, NSLICE);
        k2_reduce<<<rg, 256, 0, stream>>>(ws, nblk);
        k2_chol <<<16, 64, 0, stream>>>(ws, nblk);
    }
    k3_apply<<<1024, 256, 0, stream>>>(x, ws, out);
}

// Round 7
// 148.741 us; speedup vs baseline: 1.2376x; 1.2376x over previous
//
#include <hip/hip_runtime.h>

// DecorrelationNormalization (group whitening), x: [32,64,64,256] f32 NHWC.
// N = 131072 rows of 256 channels (1 KB each), 16 groups of m=16.
// R7: k1 accumulator set shrunk 64->40 regs/lane by partitioning the
// covariance TRIANGLE across the quad (xor-class tournament; block-diag
// entries computed by both partner lanes and folded with weight 0.5).
// This makes room for the 4-deep row prefetch WITHOUT spilling (R6 spilled:
// WRITE_SIZE 107MB). k3 reverted to the proven R5 form (no spill, ~35us).

#define NROWS   131072
#define DENOMF  131071.0f
#define EPSV    0.001f

// ws float offsets
#define OFF_INV    0        // [16][256] inv_sqrt row-major
#define OFF_BIAS   4096     // [16][16]  bias_i = sum_k inv[i][k]*mu[k]
#define OFF_TRIM   4352     // [2432] combined tri+sx (atomic fallback mode)
#define OFF_RED    8192     // [8][2432] slice-reduced partials
#define OFF_PART   27648    // [nblk][2432] per-block partials
#define COMB       2432     // 16*136 tri + 256 sx
#define NSLICE     8

__device__ __forceinline__ float4 shfl_xor4(float4 v, int m) {
    float4 r;
    r.x = __shfl_xor(v.x, m, 64);
    r.y = __shfl_xor(v.y, m, 64);
    r.z = __shfl_xor(v.z, m, 64);
    r.w = __shfl_xor(v.w, m, 64);
    return r;
}

#define DOT4(O, A, V) \
    O = fmaf(A.x, V.x, O); O = fmaf(A.y, V.y, O); \
    O = fmaf(A.z, V.z, O); O = fmaf(A.w, V.w, O)

__device__ __forceinline__ void tri_at(float* sacc, int g, int A, int B, float v) {
    const int lo = (A < B) ? A : B;
    const int hi = (A < B) ? B : A;
    atomicAdd(&sacc[g * 136 + lo * 16 - (lo * (lo - 1)) / 2 + (hi - lo)], v);
}

// ---------------- Phase 1: stats ----------------
// grid nblk x 512 thr (8 waves). Wave owns a contiguous 32-row strip,
// 4 rows/iter with 4-row-ahead prefetch. Lane l: channels [4l,4l+4),
// quad q = l&3 within group g = l>>2.
// Per xor-class d: lane accumulates v0[i]*vd[j] for {i==j (x0.5 at fold)}
// and {i<j}; absolute pair = (4q+i, 4(q^d)+j). Covers the 136-triangle
// exactly once per quad.
__global__ __launch_bounds__(512, 4) void k1_stats(const float* __restrict__ x,
                                                   float* __restrict__ ws, int nblk) {
    __shared__ float sacc[COMB];        // [0:2176) tri, [2176:2432) sx
    const int tid = threadIdx.x;
    for (int t = tid; t < COMB; t += 512) sacc[t] = 0.0f;
    __syncthreads();

    const int lane = tid & 63, wv = tid >> 6;
    const int q = lane & 3, g = lane >> 2;
    const int rpb   = NROWS / gridDim.x;   // rows per block (256)
    const int rpw   = rpb / 8;             // rows per wave (32, contiguous)
    const int iters = rpw / 4;             // 8
    const size_t rowbase = (size_t)blockIdx.x * rpb + (size_t)wv * rpw;
    const float4* wp = reinterpret_cast<const float4*>(x) + rowbase * 64 + lane;

    // class 0 (own quarter triangle): 10
    float a0_00=0, a0_01=0, a0_02=0, a0_03=0, a0_11=0, a0_12=0, a0_13=0,
          a0_22=0, a0_23=0, a0_33=0;
    // classes 1..3: diag(4) + i<j(6) each
    float a1_00=0, a1_11=0, a1_22=0, a1_33=0,
          a1_01=0, a1_02=0, a1_03=0, a1_12=0, a1_13=0, a1_23=0;
    float a2_00=0, a2_11=0, a2_22=0, a2_33=0,
          a2_01=0, a2_02=0, a2_03=0, a2_12=0, a2_13=0, a2_23=0;
    float a3_00=0, a3_11=0, a3_22=0, a3_33=0,
          a3_01=0, a3_02=0, a3_03=0, a3_12=0, a3_13=0, a3_23=0;
    float4 s4v = {0, 0, 0, 0};

#define CLS(P, VD)                                                            \
    P##_00 = fmaf(v0.x, VD.x, P##_00); P##_11 = fmaf(v0.y, VD.y, P##_11);     \
    P##_22 = fmaf(v0.z, VD.z, P##_22); P##_33 = fmaf(v0.w, VD.w, P##_33);     \
    P##_01 = fmaf(v0.x, VD.y, P##_01); P##_02 = fmaf(v0.x, VD.z, P##_02);     \
    P##_03 = fmaf(v0.x, VD.w, P##_03); P##_12 = fmaf(v0.y, VD.z, P##_12);     \
    P##_13 = fmaf(v0.y, VD.w, P##_13); P##_23 = fmaf(v0.z, VD.w, P##_23)

#define PROC1(V)                                                              \
    {                                                                         \
        float4 v0 = (V);                                                      \
        float4 v1 = shfl_xor4(v0, 1);                                         \
        float4 v2 = shfl_xor4(v0, 2);                                         \
        float4 v3 = shfl_xor4(v0, 3);                                         \
        s4v.x += v0.x; s4v.y += v0.y; s4v.z += v0.z; s4v.w += v0.w;           \
        CLS(a0, v0); CLS(a1, v1); CLS(a2, v2); CLS(a3, v3);                   \
    }

    float4 c0 = wp[0], c1 = wp[64], c2 = wp[128], c3 = wp[192];
    for (int i = 0; i < iters; ++i) {
        float4 n0, n1, n2, n3;
        const bool more = (i + 1 < iters);
        if (more) {
            const float4* np = wp + (size_t)(i + 1) * 256;
            n0 = np[0]; n1 = np[64]; n2 = np[128]; n3 = np[192];
        }
        PROC1(c0); PROC1(c1); PROC1(c2); PROC1(c3);
        if (more) { c0 = n0; c1 = n1; c2 = n2; c3 = n3; }
    }
#undef PROC1
#undef CLS

    // fold into the per-group triangle
    {
        const int qa = 4 * q;
        // class 0: absolute (qa+i, qa+j), weight 1
        tri_at(sacc, g, qa + 0, qa + 0, a0_00); tri_at(sacc, g, qa + 0, qa + 1, a0_01);
        tri_at(sacc, g, qa + 0, qa + 2, a0_02); tri_at(sacc, g, qa + 0, qa + 3, a0_03);
        tri_at(sacc, g, qa + 1, qa + 1, a0_11); tri_at(sacc, g, qa + 1, qa + 2, a0_12);
        tri_at(sacc, g, qa + 1, qa + 3, a0_13); tri_at(sacc, g, qa + 2, qa + 2, a0_22);
        tri_at(sacc, g, qa + 2, qa + 3, a0_23); tri_at(sacc, g, qa + 3, qa + 3, a0_33);
#define FOLDD(P, D)                                                           \
        {                                                                     \
            const int qb = 4 * (q ^ (D));                                     \
            tri_at(sacc, g, qa + 0, qb + 0, P##_00 * 0.5f);                   \
            tri_at(sacc, g, qa + 1, qb + 1, P##_11 * 0.5f);                   \
            tri_at(sacc, g, qa + 2, qb + 2, P##_22 * 0.5f);                   \
            tri_at(sacc, g, qa + 3, qb + 3, P##_33 * 0.5f);                   \
            tri_at(sacc, g, qa + 0, qb + 1, P##_01);                          \
            tri_at(sacc, g, qa + 0, qb + 2, P##_02);                          \
            tri_at(sacc, g, qa + 0, qb + 3, P##_03);                          \
            tri_at(sacc, g, qa + 1, qb + 2, P##_12);                          \
            tri_at(sacc, g, qa + 1, qb + 3, P##_13);                          \
            tri_at(sacc, g, qa + 2, qb + 3, P##_23);                          \
        }
        FOLDD(a1, 1); FOLDD(a2, 2); FOLDD(a3, 3);
#undef FOLDD
    }
    atomicAdd(&sacc[2176 + 4 * lane + 0], s4v.x);
    atomicAdd(&sacc[2176 + 4 * lane + 1], s4v.y);
    atomicAdd(&sacc[2176 + 4 * lane + 2], s4v.z);
    atomicAdd(&sacc[2176 + 4 * lane + 3], s4v.w);
    __syncthreads();

    if (nblk > 0) {
        float* dst = ws + OFF_PART + (size_t)blockIdx.x * COMB;
        for (int t = tid; t < COMB; t += 512) dst[t] = sacc[t];
    } else {
        for (int t = tid; t < COMB; t += 512) atomicAdd(&ws[OFF_TRIM + t], sacc[t]);
    }
}

// ---------------- Phase 2a: parallel partial reduction ----------------
__global__ __launch_bounds__(256, 4) void k2_reduce(float* __restrict__ ws, int nblk) {
    const int t = blockIdx.x * 256 + threadIdx.x;
    if (t >= COMB) return;
    const int per = nblk / NSLICE;
    const float* p = ws + OFF_PART + (size_t)(blockIdx.y * per) * COMB + t;
    float sum = 0.0f;
#pragma unroll 8
    for (int b = 0; b < per; ++b) sum += p[(size_t)b * COMB];
    ws[OFF_RED + (size_t)blockIdx.y * COMB + t] = sum;
}

// ---------------- Phase 2b: cov -> cholesky -> inverse -> bias ----------------
__global__ void k2_chol(float* __restrict__ ws, int nblk) {
    __shared__ float ct[136];
    __shared__ float cs[16];
    const int g = blockIdx.x, tid = threadIdx.x;

    if (nblk > 0) {
        for (int e = tid; e < 152; e += 64) {
            const int src = (e < 136) ? (g * 136 + e) : (2176 + g * 16 + (e - 136));
            float sum = 0.0f;
#pragma unroll
            for (int y = 0; y < NSLICE; ++y) sum += ws[OFF_RED + (size_t)y * COMB + src];
            if (e < 136) ct[e] = sum; else cs[e - 136] = sum;
        }
    } else {
        for (int e = tid; e < 152; e += 64) {
            const int src = (e < 136) ? (g * 136 + e) : (2176 + g * 16 + (e - 136));
            float v = ws[OFF_TRIM + src];
            if (e < 136) ct[e] = v; else cs[e - 136] = v;
        }
    }
    __syncthreads();

    const int ii = tid & 15;
    const float inv_denom = 1.0f / DENOMF;
    const float mu_l = cs[ii] * (1.0f / (float)NROWS);

    float arow[16];
#pragma unroll
    for (int k = 0; k < 16; ++k) {
        const int lo = (ii < k) ? ii : k;
        const int hi = (ii < k) ? k : ii;
        float sxx = ct[lo * 16 - (lo * (lo - 1)) / 2 + (hi - lo)];
        float mu_k = __shfl(mu_l, k, 64);
        float cv = (sxx - (float)NROWS * mu_l * mu_k) * inv_denom;   // /(N-1)
        cv = cv * (1.0f - EPSV) + ((k == ii) ? EPSV : 0.0f);         // shrink
        arow[k] = cv * inv_denom;                                    // faithful 2nd /(N-1)
    }

    float lrow[16];
#pragma unroll
    for (int j = 0; j < 16; ++j) {
        float diag = __shfl(arow[j], j, 64);
        float ljj  = sqrtf(diag);
        float lij  = (ii == j) ? ljj : arow[j] / ljj;
        lrow[j] = lij;
#pragma unroll
        for (int k = j + 1; k < 16; ++k) {
            float lkj = __shfl(lij, k, 64);
            arow[k] = fmaf(-lij, lkj, arow[k]);
        }
    }

    float xcol[16];
#pragma unroll
    for (int i2 = 0; i2 < 16; ++i2) {
        float ssum = (ii == i2) ? 1.0f : 0.0f;
#pragma unroll
        for (int k = 0; k < 16; ++k) {
            if (k < i2) {
                float Lik = __shfl(lrow[k], i2, 64);
                ssum = fmaf(-Lik, xcol[k], ssum);
            }
        }
        float Lii = __shfl(lrow[i2], i2, 64);
        xcol[i2] = (i2 >= ii) ? ssum / Lii : 0.0f;
    }

    float* invg = ws + OFF_INV + g * 256;
#pragma unroll
    for (int i2 = 0; i2 < 16; ++i2) {
        if (tid < 16) invg[i2 * 16 + tid] = xcol[i2];
        float bi = xcol[i2] * mu_l;
        bi += __shfl_xor(bi, 1, 64);
        bi += __shfl_xor(bi, 2, 64);
        bi += __shfl_xor(bi, 4, 64);
        bi += __shfl_xor(bi, 8, 64);
        if (tid == 0) ws[OFF_BIAS + g * 16 + i2] = bi;
    }
}

// ---------------- Phase 3: apply out = inv*x - bias ----------------
// R5 form (proven no-spill, ~35us): grid 1024 x 256 thr, 1-deep prefetch,
// inv rows in registers. ir<r><m> = inv row 4q+r, cols 4(q^m)..+4.
__global__ __launch_bounds__(256, 4) void k3_apply(const float* __restrict__ x,
                                                   const float* __restrict__ ws,
                                                   float* __restrict__ out) {
    const int tid = threadIdx.x, lane = tid & 63, wv = tid >> 6;
    const int q = lane & 3, g = lane >> 2;

    const float* invg = ws + OFF_INV + g * 256;
#define LOADIR(R, M) \
    *reinterpret_cast<const float4*>(invg + (4 * q + (R)) * 16 + 4 * (q ^ (M)))
    float4 ir00 = LOADIR(0, 0), ir01 = LOADIR(0, 1), ir02 = LOADIR(0, 2), ir03 = LOADIR(0, 3);
    float4 ir10 = LOADIR(1, 0), ir11 = LOADIR(1, 1), ir12 = LOADIR(1, 2), ir13 = LOADIR(1, 3);
    float4 ir20 = LOADIR(2, 0), ir21 = LOADIR(2, 1), ir22 = LOADIR(2, 2), ir23 = LOADIR(2, 3);
    float4 ir30 = LOADIR(3, 0), ir31 = LOADIR(3, 1), ir32 = LOADIR(3, 2), ir33 = LOADIR(3, 3);
#undef LOADIR
    float4 b4 = *reinterpret_cast<const float4*>(ws + OFF_BIAS + g * 16 + 4 * q);

    const int rpb   = NROWS / gridDim.x;   // 128
    const int iters = rpb / 4;             // 32
    const size_t rowbase = (size_t)blockIdx.x * rpb;
    const float4* xp = reinterpret_cast<const float4*>(x) + rowbase * 64 + lane;
    float4*       op = reinterpret_cast<float4*>(out)     + rowbase * 64 + lane;

    float4 cur = xp[(size_t)wv * 64];
    for (int i = 0; i < iters; ++i) {
        float4 nxt = make_float4(0.f, 0.f, 0.f, 0.f);
        if (i + 1 < iters) nxt = xp[(size_t)((i + 1) * 4 + wv) * 64];

        float4 v0 = cur;
        float4 v1 = shfl_xor4(cur, 1);
        float4 v2 = shfl_xor4(cur, 2);
        float4 v3 = shfl_xor4(cur, 3);

        float o0 = -b4.x, o1 = -b4.y, o2 = -b4.z, o3 = -b4.w;
        DOT4(o0, ir00, v0); DOT4(o0, ir01, v1); DOT4(o0, ir02, v2); DOT4(o0, ir03, v3);
        DOT4(o1, ir10, v0); DOT4(o1, ir11, v1); DOT4(o1, ir12, v2); DOT4(o1, ir13, v3);
        DOT4(o2, ir20, v0); DOT4(o2, ir21, v1); DOT4(o2, ir22, v2); DOT4(o2, ir23, v3);
        DOT4(o3, ir30, v0); DOT4(o3, ir31, v1); DOT4(o3, ir32, v2); DOT4(o3, ir33, v3);

        op[(size_t)(i * 4 + wv) * 64] = make_float4(o0, o1, o2, o3);
        cur = nxt;
    }
}

extern "C" void kernel_launch(void* const* d_in, const int* in_sizes, int n_in,
                              void* d_out, int out_size, void* d_ws, size_t ws_size,
                              hipStream_t stream) {
    const float* x = (const float*)d_in[0];
    float* out = (float*)d_out;
    float* ws  = (float*)d_ws;

    int nblk = 0;
    if (ws_size >= (size_t)(OFF_PART + 512 * COMB) * sizeof(float)) nblk = 512;
    else if (ws_size >= (size_t)(OFF_PART + 256 * COMB) * sizeof(float)) nblk = 256;

    if (nblk == 0) {
        hipMemsetAsync(ws + OFF_TRIM, 0, COMB * sizeof(float), stream);
        k1_stats<<<512, 512, 0, stream>>>(x, ws, 0);
        k2_chol <<<16, 64, 0, stream>>>(ws, 0);
    } else {
        k1_stats<<<nblk, 512, 0, stream>>>(x, ws, nblk);
        dim3 rg((COMB + 255) / 256, NSLICE);
        k2_reduce<<<rg, 256, 0, stream>>>(ws, nblk);
        k2_chol <<<16, 64, 0, stream>>>(ws, nblk);
    }
    k3_apply<<<1024, 256, 0, stream>>>(x, ws, out);
}

// Round 8
// 122.496 us; speedup vs baseline: 1.5027x; 1.2142x over previous
//
#include <hip/hip_runtime.h>

// DecorrelationNormalization (group whitening), x: [32,64,64,256] f32 NHWC.
// N = 131072 rows of 256 channels (1 KB each), 16 groups of m=16.
// R8: replace __shfl_xor (DS pipe + lgkmcnt waits) with DPP quad_perm on
// the VALU for the intra-quad xor-1/2/3 exchanges, in BOTH k1 and k3.
// k1 rebuilt on k3's proven skeleton (256 thr, wave-interleaved rows,
// 2-deep prefetch) with the R7 40-acc triangle tournament (numerics equal).

#define NROWS   131072
#define DENOMF  131071.0f
#define EPSV    0.001f

// ws float offsets
#define OFF_INV    0        // [16][256] inv_sqrt row-major
#define OFF_BIAS   4096     // [16][16]  bias_i = sum_k inv[i][k]*mu[k]
#define OFF_TRIM   4352     // [2432] combined tri+sx (atomic fallback mode)
#define OFF_RED    8192     // [8][2432] slice-reduced partials
#define OFF_PART   27648    // [nblk][2432] per-block partials
#define COMB       2432     // 16*136 tri + 256 sx
#define NSLICE     8

// DPP quad_perm cross-lane: xor1 = [1,0,3,2] = 0xB1, xor2 = [2,3,0,1] = 0x4E,
// xor3 = [3,2,1,0] = 0x1B. VALU op — no DS pipe, no lgkmcnt.
template <int CTRL>
__device__ __forceinline__ float dpp1(float v) {
    int iv = __builtin_bit_cast(int, v);
    int r = __builtin_amdgcn_update_dpp(iv, iv, CTRL, 0xF, 0xF, false);
    return __builtin_bit_cast(float, r);
}
template <int CTRL>
__device__ __forceinline__ float4 dpp4(float4 v) {
    float4 r;
    r.x = dpp1<CTRL>(v.x);
    r.y = dpp1<CTRL>(v.y);
    r.z = dpp1<CTRL>(v.z);
    r.w = dpp1<CTRL>(v.w);
    return r;
}

#define DOT4(O, A, V) \
    O = fmaf(A.x, V.x, O); O = fmaf(A.y, V.y, O); \
    O = fmaf(A.z, V.z, O); O = fmaf(A.w, V.w, O)

__device__ __forceinline__ void tri_at(float* sacc, int g, int A, int B, float v) {
    const int lo = (A < B) ? A : B;
    const int hi = (A < B) ? B : A;
    atomicAdd(&sacc[g * 136 + lo * 16 - (lo * (lo - 1)) / 2 + (hi - lo)], v);
}

// ---------------- Phase 1: stats ----------------
// grid nblk x 256 thr (4 waves). Wave wv: rows rowbase + i*4 + wv (k3's
// interleave), 2-deep prefetch. Lane l: channels [4l,4l+4), quad q = l&3,
// group g = l>>2. Per xor-class d lane accumulates v0[i]*vd[j] (i<=j),
// absolute pair (4q+i, 4(q^d)+j); block-diagonals folded with 0.5.
__global__ __launch_bounds__(256, 4) void k1_stats(const float* __restrict__ x,
                                                   float* __restrict__ ws, int nblk) {
    __shared__ float sacc[COMB];        // [0:2176) tri, [2176:2432) sx
    const int tid = threadIdx.x;
    for (int t = tid; t < COMB; t += 256) sacc[t] = 0.0f;
    __syncthreads();

    const int lane = tid & 63, wv = tid >> 6;
    const int q = lane & 3, g = lane >> 2;
    const int rpb   = NROWS / gridDim.x;   // 256 at nblk=512
    const int iters = rpb / 4;             // 64
    const size_t rowbase = (size_t)blockIdx.x * rpb;
    const float4* xp = reinterpret_cast<const float4*>(x) + rowbase * 64 + lane;

    // class 0 (own quarter triangle): 10
    float a0_00=0, a0_01=0, a0_02=0, a0_03=0, a0_11=0, a0_12=0, a0_13=0,
          a0_22=0, a0_23=0, a0_33=0;
    // classes 1..3: diag(4) + i<j(6) each
    float a1_00=0, a1_11=0, a1_22=0, a1_33=0,
          a1_01=0, a1_02=0, a1_03=0, a1_12=0, a1_13=0, a1_23=0;
    float a2_00=0, a2_11=0, a2_22=0, a2_33=0,
          a2_01=0, a2_02=0, a2_03=0, a2_12=0, a2_13=0, a2_23=0;
    float a3_00=0, a3_11=0, a3_22=0, a3_33=0,
          a3_01=0, a3_02=0, a3_03=0, a3_12=0, a3_13=0, a3_23=0;
    float4 s4v = {0, 0, 0, 0};

#define CLS(P, VD)                                                            \
    P##_00 = fmaf(v0.x, VD.x, P##_00); P##_11 = fmaf(v0.y, VD.y, P##_11);     \
    P##_22 = fmaf(v0.z, VD.z, P##_22); P##_33 = fmaf(v0.w, VD.w, P##_33);     \
    P##_01 = fmaf(v0.x, VD.y, P##_01); P##_02 = fmaf(v0.x, VD.z, P##_02);     \
    P##_03 = fmaf(v0.x, VD.w, P##_03); P##_12 = fmaf(v0.y, VD.z, P##_12);     \
    P##_13 = fmaf(v0.y, VD.w, P##_13); P##_23 = fmaf(v0.z, VD.w, P##_23)

#define PROC1(V)                                                              \
    {                                                                         \
        float4 v0 = (V);                                                      \
        float4 v1 = dpp4<0xB1>(v0);                                           \
        float4 v2 = dpp4<0x4E>(v0);                                           \
        float4 v3 = dpp4<0x1B>(v0);                                           \
        s4v.x += v0.x; s4v.y += v0.y; s4v.z += v0.z; s4v.w += v0.w;           \
        CLS(a0, v0); CLS(a1, v1); CLS(a2, v2); CLS(a3, v3);                   \
    }

    float4 c0 = xp[(size_t)wv * 64];
    float4 c1 = xp[(size_t)(4 + wv) * 64];
    for (int i = 0; i < iters; ++i) {
        float4 nx = make_float4(0.f, 0.f, 0.f, 0.f);
        if (i + 2 < iters) nx = xp[(size_t)((i + 2) * 4 + wv) * 64];
        PROC1(c0);
        c0 = c1; c1 = nx;
    }
#undef PROC1
#undef CLS

    // fold into the per-group triangle
    {
        const int qa = 4 * q;
        tri_at(sacc, g, qa + 0, qa + 0, a0_00); tri_at(sacc, g, qa + 0, qa + 1, a0_01);
        tri_at(sacc, g, qa + 0, qa + 2, a0_02); tri_at(sacc, g, qa + 0, qa + 3, a0_03);
        tri_at(sacc, g, qa + 1, qa + 1, a0_11); tri_at(sacc, g, qa + 1, qa + 2, a0_12);
        tri_at(sacc, g, qa + 1, qa + 3, a0_13); tri_at(sacc, g, qa + 2, qa + 2, a0_22);
        tri_at(sacc, g, qa + 2, qa + 3, a0_23); tri_at(sacc, g, qa + 3, qa + 3, a0_33);
#define FOLDD(P, D)                                                           \
        {                                                                     \
            const int qb = 4 * (q ^ (D));                                     \
            tri_at(sacc, g, qa + 0, qb + 0, P##_00 * 0.5f);                   \
            tri_at(sacc, g, qa + 1, qb + 1, P##_11 * 0.5f);                   \
            tri_at(sacc, g, qa + 2, qb + 2, P##_22 * 0.5f);                   \
            tri_at(sacc, g, qa + 3, qb + 3, P##_33 * 0.5f);                   \
            tri_at(sacc, g, qa + 0, qb + 1, P##_01);                          \
            tri_at(sacc, g, qa + 0, qb + 2, P##_02);                          \
            tri_at(sacc, g, qa + 0, qb + 3, P##_03);                          \
            tri_at(sacc, g, qa + 1, qb + 2, P##_12);                          \
            tri_at(sacc, g, qa + 1, qb + 3, P##_13);                          \
            tri_at(sacc, g, qa + 2, qb + 3, P##_23);                          \
        }
        FOLDD(a1, 1); FOLDD(a2, 2); FOLDD(a3, 3);
#undef FOLDD
    }
    atomicAdd(&sacc[2176 + 4 * lane + 0], s4v.x);
    atomicAdd(&sacc[2176 + 4 * lane + 1], s4v.y);
    atomicAdd(&sacc[2176 + 4 * lane + 2], s4v.z);
    atomicAdd(&sacc[2176 + 4 * lane + 3], s4v.w);
    __syncthreads();

    if (nblk > 0) {
        float* dst = ws + OFF_PART + (size_t)blockIdx.x * COMB;
        for (int t = tid; t < COMB; t += 256) dst[t] = sacc[t];
    } else {
        for (int t = tid; t < COMB; t += 256) atomicAdd(&ws[OFF_TRIM + t], sacc[t]);
    }
}

// ---------------- Phase 2a: parallel partial reduction ----------------
__global__ __launch_bounds__(256, 4) void k2_reduce(float* __restrict__ ws, int nblk) {
    const int t = blockIdx.x * 256 + threadIdx.x;
    if (t >= COMB) return;
    const int per = nblk / NSLICE;
    const float* p = ws + OFF_PART + (size_t)(blockIdx.y * per) * COMB + t;
    float sum = 0.0f;
#pragma unroll 8
    for (int b = 0; b < per; ++b) sum += p[(size_t)b * COMB];
    ws[OFF_RED + (size_t)blockIdx.y * COMB + t] = sum;
}

// ---------------- Phase 2b: cov -> cholesky -> inverse -> bias ----------------
__global__ void k2_chol(float* __restrict__ ws, int nblk) {
    __shared__ float ct[136];
    __shared__ float cs[16];
    const int g = blockIdx.x, tid = threadIdx.x;

    if (nblk > 0) {
        for (int e = tid; e < 152; e += 64) {
            const int src = (e < 136) ? (g * 136 + e) : (2176 + g * 16 + (e - 136));
            float sum = 0.0f;
#pragma unroll
            for (int y = 0; y < NSLICE; ++y) sum += ws[OFF_RED + (size_t)y * COMB + src];
            if (e < 136) ct[e] = sum; else cs[e - 136] = sum;
        }
    } else {
        for (int e = tid; e < 152; e += 64) {
            const int src = (e < 136) ? (g * 136 + e) : (2176 + g * 16 + (e - 136));
            float v = ws[OFF_TRIM + src];
            if (e < 136) ct[e] = v; else cs[e - 136] = v;
        }
    }
    __syncthreads();

    const int ii = tid & 15;
    const float inv_denom = 1.0f / DENOMF;
    const float mu_l = cs[ii] * (1.0f / (float)NROWS);

    float arow[16];
#pragma unroll
    for (int k = 0; k < 16; ++k) {
        const int lo = (ii < k) ? ii : k;
        const int hi = (ii < k) ? k : ii;
        float sxx = ct[lo * 16 - (lo * (lo - 1)) / 2 + (hi - lo)];
        float mu_k = __shfl(mu_l, k, 64);
        float cv = (sxx - (float)NROWS * mu_l * mu_k) * inv_denom;   // /(N-1)
        cv = cv * (1.0f - EPSV) + ((k == ii) ? EPSV : 0.0f);         // shrink
        arow[k] = cv * inv_denom;                                    // faithful 2nd /(N-1)
    }

    float lrow[16];
#pragma unroll
    for (int j = 0; j < 16; ++j) {
        float diag = __shfl(arow[j], j, 64);
        float ljj  = sqrtf(diag);
        float lij  = (ii == j) ? ljj : arow[j] / ljj;
        lrow[j] = lij;
#pragma unroll
        for (int k = j + 1; k < 16; ++k) {
            float lkj = __shfl(lij, k, 64);
            arow[k] = fmaf(-lij, lkj, arow[k]);
        }
    }

    float xcol[16];
#pragma unroll
    for (int i2 = 0; i2 < 16; ++i2) {
        float ssum = (ii == i2) ? 1.0f : 0.0f;
#pragma unroll
        for (int k = 0; k < 16; ++k) {
            if (k < i2) {
                float Lik = __shfl(lrow[k], i2, 64);
                ssum = fmaf(-Lik, xcol[k], ssum);
            }
        }
        float Lii = __shfl(lrow[i2], i2, 64);
        xcol[i2] = (i2 >= ii) ? ssum / Lii : 0.0f;
    }

    float* invg = ws + OFF_INV + g * 256;
#pragma unroll
    for (int i2 = 0; i2 < 16; ++i2) {
        if (tid < 16) invg[i2 * 16 + tid] = xcol[i2];
        float bi = xcol[i2] * mu_l;
        bi += __shfl_xor(bi, 1, 64);
        bi += __shfl_xor(bi, 2, 64);
        bi += __shfl_xor(bi, 4, 64);
        bi += __shfl_xor(bi, 8, 64);
        if (tid == 0) ws[OFF_BIAS + g * 16 + i2] = bi;
    }
}

// ---------------- Phase 3: apply out = inv*x - bias ----------------
// grid 1024 x 256 thr (4 waves), 1-deep prefetch, DPP quad_perm exchange.
// ir<r><m> = inv row 4q+r, cols 4(q^m)..+4.
__global__ __launch_bounds__(256, 4) void k3_apply(const float* __restrict__ x,
                                                   const float* __restrict__ ws,
                                                   float* __restrict__ out) {
    const int tid = threadIdx.x, lane = tid & 63, wv = tid >> 6;
    const int q = lane & 3, g = lane >> 2;

    const float* invg = ws + OFF_INV + g * 256;
#define LOADIR(R, M) \
    *reinterpret_cast<const float4*>(invg + (4 * q + (R)) * 16 + 4 * (q ^ (M)))
    float4 ir00 = LOADIR(0, 0), ir01 = LOADIR(0, 1), ir02 = LOADIR(0, 2), ir03 = LOADIR(0, 3);
    float4 ir10 = LOADIR(1, 0), ir11 = LOADIR(1, 1), ir12 = LOADIR(1, 2), ir13 = LOADIR(1, 3);
    float4 ir20 = LOADIR(2, 0), ir21 = LOADIR(2, 1), ir22 = LOADIR(2, 2), ir23 = LOADIR(2, 3);
    float4 ir30 = LOADIR(3, 0), ir31 = LOADIR(3, 1), ir32 = LOADIR(3, 2), ir33 = LOADIR(3, 3);
#undef LOADIR
    float4 b4 = *reinterpret_cast<const float4*>(ws + OFF_BIAS + g * 16 + 4 * q);

    const int rpb   = NROWS / gridDim.x;   // 128
    const int iters = rpb / 4;             // 32
    const size_t rowbase = (size_t)blockIdx.x * rpb;
    const float4* xp = reinterpret_cast<const float4*>(x) + rowbase * 64 + lane;
    float4*       op = reinterpret_cast<float4*>(out)     + rowbase * 64 + lane;

    float4 cur = xp[(size_t)wv * 64];
    for (int i = 0; i < iters; ++i) {
        float4 nxt = make_float4(0.f, 0.f, 0.f, 0.f);
        if (i + 1 < iters) nxt = xp[(size_t)((i + 1) * 4 + wv) * 64];

        float4 v0 = cur;
        float4 v1 = dpp4<0xB1>(cur);
        float4 v2 = dpp4<0x4E>(cur);
        float4 v3 = dpp4<0x1B>(cur);

        float o0 = -b4.x, o1 = -b4.y, o2 = -b4.z, o3 = -b4.w;
        DOT4(o0, ir00, v0); DOT4(o0, ir01, v1); DOT4(o0, ir02, v2); DOT4(o0, ir03, v3);
        DOT4(o1, ir10, v0); DOT4(o1, ir11, v1); DOT4(o1, ir12, v2); DOT4(o1, ir13, v3);
        DOT4(o2, ir20, v0); DOT4(o2, ir21, v1); DOT4(o2, ir22, v2); DOT4(o2, ir23, v3);
        DOT4(o3, ir30, v0); DOT4(o3, ir31, v1); DOT4(o3, ir32, v2); DOT4(o3, ir33, v3);

        op[(size_t)(i * 4 + wv) * 64] = make_float4(o0, o1, o2, o3);
        cur = nxt;
    }
}

extern "C" void kernel_launch(void* const* d_in, const int* in_sizes, int n_in,
                              void* d_out, int out_size, void* d_ws, size_t ws_size,
                              hipStream_t stream) {
    const float* x = (const float*)d_in[0];
    float* out = (float*)d_out;
    float* ws  = (float*)d_ws;

    int nblk = 0;
    if (ws_size >= (size_t)(OFF_PART + 512 * COMB) * sizeof(float)) nblk = 512;
    else if (ws_size >= (size_t)(OFF_PART + 256 * COMB) * sizeof(float)) nblk = 256;

    if (nblk == 0) {
        hipMemsetAsync(ws + OFF_TRIM, 0, COMB * sizeof(float), stream);
        k1_stats<<<512, 256, 0, stream>>>(x, ws, 0);
        k2_chol <<<16, 64, 0, stream>>>(ws, 0);
    } else {
        k1_stats<<<nblk, 256, 0, stream>>>(x, ws, nblk);
        dim3 rg((COMB + 255) / 256, NSLICE);
        k2_reduce<<<rg, 256, 0, stream>>>(ws, nblk);
        k2_chol <<<16, 64, 0, stream>>>(ws, nblk);
    }
    k3_apply<<<1024, 256, 0, stream>>>(x, ws, out);
}